// Round 5
// baseline (572.411 us; speedup 1.0000x reference)
//
#include <hip/hip_runtime.h>

typedef __attribute__((ext_vector_type(8))) short short8;
typedef __attribute__((ext_vector_type(4))) float f32x4;

#define T_LEN 320

__device__ inline unsigned short bf16_rne(float x) {
    union { float f; unsigned u; } a; a.f = x;
    unsigned r = a.u + 0x7fffu + ((a.u >> 16) & 1u);
    return (unsigned short)(r >> 16);
}
__device__ inline float bf16_to_f(unsigned short h) {
    union { unsigned u; float f; } a; a.u = ((unsigned)h) << 16;
    return a.f;
}
// 3-way split: x = h + m + l + O(2^-27 |x|)
__device__ inline void split3(float x, unsigned short &h, unsigned short &m, unsigned short &l) {
    h = bf16_rne(x);
    const float r1 = x - bf16_to_f(h);
    m = bf16_rne(r1);
    l = bf16_rne(r1 - bf16_to_f(m));
}

// ---------------------------------------------------------------------------
// Kernel 1: conv1(5,64->32)+bn1+relu -> conv2(3,32->16)+bn2+relu
// 3-way-split bf16 MFMA (6 products, 2 accumulators -> 3-deep chains).
// Wave roles (8 waves = 2 nh x 4 kq): kq=0..2 conv1 K-split {0-2},{3-6},{7-9};
// kq=3 conv2. Epilogue (redbuf sum + bn1 + split3 + c1 write) distributed
// over ALL 8 waves. Async staging: global loads issued at loop top (hidden
// under MFMA), LDS writes after B2. One row/block. e_ws layout (B,16,T) f32.
// ---------------------------------------------------------------------------
struct ConvSmem {
    unsigned short xh[70][64], xm[70][64], xl[70][64];   // x slab, swizzled
    unsigned short c1h[66][32], c1m[66][32], c1l[66][32];// conv1 out slab
    float red[2][3][5][65][4];                           // [nh][src][F][lane(pad 65)][reg]
};

__device__ __forceinline__ float4 stage_load(const float* __restrict__ xrow, int t0, int fi) {
    float4 v = {0.f, 0.f, 0.f, 0.f};
    if (fi < 1120) {
        const int s = fi >> 4, cq = fi & 15;
        const int tabs = t0 - 3 + s;
        if (tabs >= 0 && tabs < T_LEN)
            v = *reinterpret_cast<const float4*>(xrow + (size_t)tabs * 64 + cq * 4);
    }
    return v;
}

__device__ __forceinline__ void stage_store(ConvSmem& sm, int fi, float4 v) {
    if (fi >= 1120) return;
    const int s = fi >> 4, cq = fi & 15;
    unsigned short h0,m0,l0,h1,m1,l1,h2,m2,l2,h3,m3,l3;
    split3(v.x, h0, m0, l0); split3(v.y, h1, m1, l1);
    split3(v.z, h2, m2, l2); split3(v.w, h3, m3, l3);
    const int off = (((cq >> 1) ^ (s & 7)) * 8) + (cq & 1) * 4;
    ushort4 hv = {h0, h1, h2, h3};
    ushort4 mv = {m0, m1, m2, m3};
    ushort4 lv = {l0, l1, l2, l3};
    *reinterpret_cast<ushort4*>(&sm.xh[s][off]) = hv;
    *reinterpret_cast<ushort4*>(&sm.xm[s][off]) = mv;
    *reinterpret_cast<ushort4*>(&sm.xl[s][off]) = lv;
}

// Distributed epilogue: all 8 waves each handle 264 of the 66x32 c1 values.
__device__ __forceinline__ void epi_all(ConvSmem& sm, int wv, int lane, int t0,
                                        int co, float s1e, float b1e) {
#pragma unroll
    for (int i = 0; i < 5; ++i) {
        const int off_l = i * 64 + lane;
        if (off_l < 264) {
            const int idx = wv * 264 + off_l;
            const int rl = idx >> 5;                 // 0..65
            const int F = rl >> 4, lg2 = (rl >> 2) & 3, reg = rl & 3;
            const int lw = lg2 * 16 + (co & 15), nh2 = co >> 4;
            const float v = sm.red[nh2][0][F][lw][reg]
                          + sm.red[nh2][1][F][lw][reg]
                          + sm.red[nh2][2][F][lw][reg];
            const int tabs = t0 - 1 + rl;
            const float val = (tabs >= 0 && tabs < T_LEN) ? fmaxf(v * s1e + b1e, 0.f) : 0.f;
            unsigned short h, m, l; split3(val, h, m, l);
            const int off2 = (((co >> 3) ^ (rl & 3)) * 8) + (co & 7);
            sm.c1h[rl][off2] = h;
            sm.c1m[rl][off2] = m;
            sm.c1l[rl][off2] = l;
        }
    }
}

template<int NKS, int SRC>
__device__ __forceinline__ void conv1_role(ConvSmem& sm, const float* __restrict__ xrow,
                                           const float* __restrict__ k1g,
                                           int wv, int lane, int nh, int ksb, int stagei,
                                           int co_e, float s1e, float b1e) {
    const int lcol = lane & 15, lg = lane >> 4;
    const int co1 = nh * 16 + lcol;

    short8 w1h[NKS], w1m[NKS], w1l[NKS];
#pragma unroll
    for (int i = 0; i < NKS; ++i) {
        const int ks = ksb + i;
        const int w = ks >> 1, cib = (ks & 1) * 32 + lg * 8;
        short8 hh, mv, lv;
#pragma unroll
        for (int j = 0; j < 8; ++j) {
            float kv = k1g[(w * 64 + cib + j) * 32 + co1];
            unsigned short h, m, l; split3(kv, h, m, l);
            hh[j] = (short)h; mv[j] = (short)m; lv[j] = (short)l;
        }
        w1h[i] = hh; w1m[i] = mv; w1l[i] = lv;
    }

    for (int ch = 0; ch < 5; ++ch) {
        const int t0 = ch * 64;
        // async staging: issue next-chunk global loads now (consumed post-B2)
        float4 g0, g1, g2;
        const bool do_stage = (stagei >= 0) && (ch < 4);
        if (do_stage) {
            g0 = stage_load(xrow, t0 + 64, stagei);
            g1 = stage_load(xrow, t0 + 64, stagei + 384);
            g2 = stage_load(xrow, t0 + 64, stagei + 768);
        }

        f32x4 a0[5], a1[5];
#pragma unroll
        for (int mi = 0; mi < 5; ++mi) {
            a0[mi] = (f32x4){0.f, 0.f, 0.f, 0.f};
            a1[mi] = (f32x4){0.f, 0.f, 0.f, 0.f};
        }
#pragma unroll
        for (int i = 0; i < NKS; ++i) {
            const int ks = ksb + i;
            const int w = ks >> 1, lb = (ks & 1) * 4 + lg;
#pragma unroll
            for (int mi = 0; mi < 5; ++mi) {
                int s = mi * 16 + lcol + w;
                if (s > 69) s = 69;                   // rows >=66 discarded in epilogue
                const int off = ((lb ^ (s & 7)) * 8);
                short8 ah = *reinterpret_cast<const short8*>(&sm.xh[s][off]);
                short8 am = *reinterpret_cast<const short8*>(&sm.xm[s][off]);
                short8 al = *reinterpret_cast<const short8*>(&sm.xl[s][off]);
                // two independent 3-chains
                a0[mi] = __builtin_amdgcn_mfma_f32_16x16x32_bf16(ah, w1h[i], a0[mi], 0, 0, 0);
                a1[mi] = __builtin_amdgcn_mfma_f32_16x16x32_bf16(ah, w1m[i], a1[mi], 0, 0, 0);
                a0[mi] = __builtin_amdgcn_mfma_f32_16x16x32_bf16(am, w1h[i], a0[mi], 0, 0, 0);
                a1[mi] = __builtin_amdgcn_mfma_f32_16x16x32_bf16(ah, w1l[i], a1[mi], 0, 0, 0);
                a0[mi] = __builtin_amdgcn_mfma_f32_16x16x32_bf16(al, w1h[i], a0[mi], 0, 0, 0);
                a1[mi] = __builtin_amdgcn_mfma_f32_16x16x32_bf16(am, w1m[i], a1[mi], 0, 0, 0);
            }
        }
        // dump partials
#pragma unroll
        for (int mi = 0; mi < 5; ++mi) {
            f32x4 sum = a0[mi] + a1[mi];
            *reinterpret_cast<f32x4*>(&sm.red[nh][SRC][mi][lane][0]) = sum;
        }
        __syncthreads();   // B2: partials visible; x slab free

        epi_all(sm, wv, lane, t0, co_e, s1e, b1e);
        if (do_stage) {
            stage_store(sm, stagei, g0);
            stage_store(sm, stagei + 384, g1);
            stage_store(sm, stagei + 768, g2);
        }
        __syncthreads();   // B3: c1 + next x slab ready
    }
}

__device__ __forceinline__ void conv2_do(ConvSmem& sm, float* __restrict__ erow, int t0p,
                                         const short8* w2h, const short8* w2m, const short8* w2l,
                                         float s2, float b2, int lane, int nh) {
    const int lcol = lane & 15, lg = lane >> 4;
    f32x4 d0[2], d1[2];
#pragma unroll
    for (int mi = 0; mi < 2; ++mi) {
        d0[mi] = (f32x4){0.f, 0.f, 0.f, 0.f};
        d1[mi] = (f32x4){0.f, 0.f, 0.f, 0.f};
    }
#pragma unroll
    for (int ks = 0; ks < 3; ++ks) {
#pragma unroll
        for (int mi = 0; mi < 2; ++mi) {
            const int sidx = nh * 32 + mi * 16 + lcol + ks;     // 0..65
            const int off = ((lg ^ (sidx & 3)) * 8);
            short8 ah = *reinterpret_cast<const short8*>(&sm.c1h[sidx][off]);
            short8 am = *reinterpret_cast<const short8*>(&sm.c1m[sidx][off]);
            short8 al = *reinterpret_cast<const short8*>(&sm.c1l[sidx][off]);
            d0[mi] = __builtin_amdgcn_mfma_f32_16x16x32_bf16(ah, w2h[ks], d0[mi], 0, 0, 0);
            d1[mi] = __builtin_amdgcn_mfma_f32_16x16x32_bf16(ah, w2m[ks], d1[mi], 0, 0, 0);
            d0[mi] = __builtin_amdgcn_mfma_f32_16x16x32_bf16(am, w2h[ks], d0[mi], 0, 0, 0);
            d1[mi] = __builtin_amdgcn_mfma_f32_16x16x32_bf16(ah, w2l[ks], d1[mi], 0, 0, 0);
            d0[mi] = __builtin_amdgcn_mfma_f32_16x16x32_bf16(al, w2h[ks], d0[mi], 0, 0, 0);
            d1[mi] = __builtin_amdgcn_mfma_f32_16x16x32_bf16(am, w2m[ks], d1[mi], 0, 0, 0);
        }
    }
#pragma unroll
    for (int mi = 0; mi < 2; ++mi) {
        f32x4 c = d0[mi] + d1[mi];
        float4 ov;
        ov.x = fmaxf(c[0] * s2 + b2, 0.f);
        ov.y = fmaxf(c[1] * s2 + b2, 0.f);
        ov.z = fmaxf(c[2] * s2 + b2, 0.f);
        ov.w = fmaxf(c[3] * s2 + b2, 0.f);
        const int t = t0p + nh * 32 + mi * 16 + lg * 4;
        *reinterpret_cast<float4*>(erow + (size_t)lcol * T_LEN + t) = ov;
    }
}

__device__ __forceinline__ void conv2_role(ConvSmem& sm, const float* __restrict__ xrow,
                                           float* __restrict__ erow,
                                           const float* __restrict__ k2g,
                                           const float* __restrict__ c2bias,
                                           const float* __restrict__ bn2s,
                                           const float* __restrict__ bn2b,
                                           const float* __restrict__ bn2m,
                                           const float* __restrict__ bn2v,
                                           int wv, int lane, int nh, int stagei,
                                           int co_e, float s1e, float b1e) {
    const int lcol = lane & 15, lg = lane >> 4;
    short8 w2h[3], w2m[3], w2l[3];
#pragma unroll
    for (int ks = 0; ks < 3; ++ks) {
        const int cib = lg * 8;
        short8 hh, mv, lv;
#pragma unroll
        for (int j = 0; j < 8; ++j) {
            float kv = k2g[(ks * 32 + cib + j) * 16 + lcol];
            unsigned short h, m, l; split3(kv, h, m, l);
            hh[j] = (short)h; mv[j] = (short)m; lv[j] = (short)l;
        }
        w2h[ks] = hh; w2m[ks] = mv; w2l[ks] = lv;
    }
    const float s2 = bn2s[lcol] * (1.0f / sqrtf(bn2v[lcol] + 1e-5f));
    const float b2 = bn2b[lcol] + (c2bias[lcol] - bn2m[lcol]) * s2;

    for (int ch = 0; ch < 5; ++ch) {
        const int t0 = ch * 64;
        float4 g0, g1, g2;
        const bool do_stage = (ch < 4);
        if (do_stage) {
            g0 = stage_load(xrow, t0 + 64, stagei);
            g1 = stage_load(xrow, t0 + 64, stagei + 384);
            g2 = stage_load(xrow, t0 + 64, stagei + 768);
        }
        if (ch > 0)
            conv2_do(sm, erow, (ch - 1) * 64, w2h, w2m, w2l, s2, b2, lane, nh);
        __syncthreads();   // B2

        epi_all(sm, wv, lane, t0, co_e, s1e, b1e);
        if (do_stage) {
            stage_store(sm, stagei, g0);
            stage_store(sm, stagei + 384, g1);
            stage_store(sm, stagei + 768, g2);
        }
        __syncthreads();   // B3
    }
    conv2_do(sm, erow, 256, w2h, w2m, w2l, s2, b2, lane, nh);   // tail chunk
}

__global__ __launch_bounds__(512, 4) void geo_alif_conv_kernel(
    const float* __restrict__ x_eeg,
    const float* __restrict__ k1g, const float* __restrict__ c1bias,
    const float* __restrict__ bn1s, const float* __restrict__ bn1b,
    const float* __restrict__ bn1m, const float* __restrict__ bn1v,
    const float* __restrict__ k2g, const float* __restrict__ c2bias,
    const float* __restrict__ bn2s, const float* __restrict__ bn2b,
    const float* __restrict__ bn2m, const float* __restrict__ bn2v,
    float* __restrict__ e_ws)
{
    __shared__ ConvSmem sm;
    const int tid = threadIdx.x, lane = tid & 63;
    const int wv = tid >> 6, nh = wv & 1, kq = wv >> 1;
    const float* xrow = x_eeg + (size_t)blockIdx.x * (T_LEN * 64);
    float* erow = e_ws + (size_t)blockIdx.x * (16 * T_LEN);

    // per-thread bn1 constants for the distributed epilogue
    const int co_e = (8 * wv + lane) & 31;
    const float s1e = bn1s[co_e] * (1.0f / sqrtf(bn1v[co_e] + 1e-5f));
    const float b1e = bn1b[co_e] + (c1bias[co_e] - bn1m[co_e]) * s1e;

    // prologue: stage chunk 0 with all 512 threads
    for (int fi = tid; fi < 1120; fi += 512)
        stage_store(sm, fi, stage_load(xrow, 0, fi));
    __syncthreads();

    const int stagei = (kq == 1) ? -1 : ((wv < 2 ? wv : wv - 2) * 64 + lane);

    if (kq == 0)      conv1_role<3, 0>(sm, xrow, k1g, wv, lane, nh, 0, stagei, co_e, s1e, b1e);
    else if (kq == 1) conv1_role<4, 1>(sm, xrow, k1g, wv, lane, nh, 3, -1,     co_e, s1e, b1e);
    else if (kq == 2) conv1_role<3, 2>(sm, xrow, k1g, wv, lane, nh, 7, stagei, co_e, s1e, b1e);
    else conv2_role(sm, xrow, erow, k2g, c2bias, bn2s, bn2b, bn2m, bn2v,
                    wv, lane, nh, stagei, co_e, s1e, b1e);
}

// ---------------------------------------------------------------------------
// Kernel 2: geo gate + ALIF scan + windowed diff-pool + fc1 + fc2
// Block: 16 batch rows x 16 hidden = 256 threads. Grid: 256.
// ---------------------------------------------------------------------------
__global__ __launch_bounds__(256) void geo_alif_scan_kernel(
    const float* __restrict__ e_ws, const float* __restrict__ x_geo,
    const float* __restrict__ geoW, const float* __restrict__ geob,
    const float* __restrict__ gam,
    const float* __restrict__ fc1W, const float* __restrict__ fc1b,
    const float* __restrict__ fc2W, const float* __restrict__ fc2b,
    float* __restrict__ out)
{
    __shared__ float gW[18][16];
    __shared__ float geo_s[16][16][16];   // [row][t_local][h]
    __shared__ float dp[16][160];         // [row][h*10+w]
    __shared__ float h1s[16][64];

    const int tid = threadIdx.x;
    for (int i = tid; i < 288; i += 256) gW[i / 16][i & 15] = geoW[i];
    __syncthreads();

    const int r = tid >> 4, h = tid & 15;
    const int b = blockIdx.x * 16 + r;
    const float* ep = e_ws + ((size_t)b * 16 + h) * T_LEN;
    const float gmv = gam[h];

    float mem = 0.f, eta = 0.f, li = 0.f, prev = 0.f, acc = 0.f;

    for (int c = 0; c < 20; ++c) {
        {
            const int rg = tid >> 4, tl = tid & 15;
            const int t = c * 16 + tl;
            const float* xg = x_geo + ((size_t)(blockIdx.x * 16 + rg) * T_LEN + t) * 18;
            float xv[18];
#pragma unroll
            for (int i = 0; i < 18; ++i) xv[i] = xg[i];
#pragma unroll
            for (int hh = 0; hh < 16; ++hh) {
                float a = geob[hh];
#pragma unroll
                for (int i = 0; i < 18; ++i) a = fmaf(xv[i], gW[i][hh], a);
                geo_s[rg][tl][hh] = 1.f / (1.f + expf(-a));
            }
        }
        __syncthreads();

        const float* ec = ep + c * 16;
#pragma unroll
        for (int q = 0; q < 4; ++q) {
            float4 ev = *reinterpret_cast<const float4*>(ec + q * 4);
            float evs[4] = {ev.x, ev.y, ev.z, ev.w};
#pragma unroll
            for (int u = 0; u < 4; ++u) {
                const int tt = c * 16 + q * 4 + u;
                const float g = geo_s[r][q * 4 + u][h];
                eta = 0.36f * eta + 0.64f * prev;
                const float th = 0.5f + 1.8f * eta - gmv * g;
                mem = 0.8f * mem + evs[u];
                const bool sp = (mem >= th);
                const float spk = sp ? 1.f : 0.f;
                prev = spk;
                mem = sp ? 0.f : mem;
                li = 0.9f * li + spk;
                acc += ((tt & 31) < 16) ? -li : li;
                if ((tt & 31) == 31) {
                    dp[r][h * 10 + (tt >> 5)] = acc * 0.0625f;
                    acc = 0.f;
                }
            }
        }
        __syncthreads();
    }

    {
        const int rr = tid >> 4, j0 = tid & 15;
        float a0 = fc1b[j0], a1 = fc1b[j0 + 16], a2 = fc1b[j0 + 32], a3 = fc1b[j0 + 48];
        for (int f = 0; f < 160; ++f) {
            const float d = dp[rr][f];
            a0 = fmaf(d, fc1W[f * 64 + j0],      a0);
            a1 = fmaf(d, fc1W[f * 64 + j0 + 16], a1);
            a2 = fmaf(d, fc1W[f * 64 + j0 + 32], a2);
            a3 = fmaf(d, fc1W[f * 64 + j0 + 48], a3);
        }
        h1s[rr][j0]      = fmaxf(a0, 0.f);
        h1s[rr][j0 + 16] = fmaxf(a1, 0.f);
        h1s[rr][j0 + 32] = fmaxf(a2, 0.f);
        h1s[rr][j0 + 48] = fmaxf(a3, 0.f);
    }
    __syncthreads();

    if (tid < 64) {
        const int rr = tid >> 2, o = tid & 3;
        float a = fc2b[o];
#pragma unroll
        for (int j = 0; j < 64; ++j) a = fmaf(h1s[rr][j], fc2W[j * 4 + o], a);
        out[((size_t)(blockIdx.x * 16 + rr)) * 4 + o] = a;
    }
}

extern "C" void kernel_launch(void* const* d_in, const int* in_sizes, int n_in,
                              void* d_out, int out_size, void* d_ws, size_t ws_size,
                              hipStream_t stream) {
    (void)in_sizes; (void)n_in; (void)out_size; (void)ws_size;
    const float* x_eeg = (const float*)d_in[0];
    const float* x_geo = (const float*)d_in[1];
    const float* k1    = (const float*)d_in[2];
    const float* c1b   = (const float*)d_in[3];
    const float* bn1s  = (const float*)d_in[4];
    const float* bn1b  = (const float*)d_in[5];
    const float* bn1m  = (const float*)d_in[6];
    const float* bn1v  = (const float*)d_in[7];
    const float* k2    = (const float*)d_in[8];
    const float* c2b   = (const float*)d_in[9];
    const float* bn2s  = (const float*)d_in[10];
    const float* bn2b  = (const float*)d_in[11];
    const float* bn2m  = (const float*)d_in[12];
    const float* bn2v  = (const float*)d_in[13];
    const float* geoW  = (const float*)d_in[14];
    const float* geob  = (const float*)d_in[15];
    const float* gam   = (const float*)d_in[16];
    const float* fc1W  = (const float*)d_in[17];
    const float* fc1b  = (const float*)d_in[18];
    const float* fc2W  = (const float*)d_in[19];
    const float* fc2b  = (const float*)d_in[20];

    float* e_ws = (float*)d_ws;   // 4096*16*320*4 = 83,886,080 bytes

    geo_alif_conv_kernel<<<4096, 512, 0, stream>>>(
        x_eeg, k1, c1b, bn1s, bn1b, bn1m, bn1v,
        k2, c2b, bn2s, bn2b, bn2m, bn2v, e_ws);

    geo_alif_scan_kernel<<<256, 256, 0, stream>>>(
        e_ws, x_geo, geoW, geob, gam, fc1W, fc1b, fc2W, fc2b, (float*)d_out);
}

// Round 7
// 391.873 us; speedup vs baseline: 1.4607x; 1.4607x over previous
//
#include <hip/hip_runtime.h>

typedef _Float16 f16;
typedef __attribute__((ext_vector_type(8))) _Float16 f16x8;
typedef __attribute__((ext_vector_type(16))) float f32x16;

#define T_LEN 320

// ---------------------------------------------------------------------------
// f16 two-limb split with scaled low limb: v = h + (l/4096), residual ~2^-24|v|
// ---------------------------------------------------------------------------
__device__ __forceinline__ void split2h(float v, unsigned short &h, unsigned short &l) {
    f16 hh = (f16)v;
    f16 ll = (f16)((v - (float)hh) * 4096.0f);
    h = __builtin_bit_cast(unsigned short, hh);
    l = __builtin_bit_cast(unsigned short, ll);
}

// ---------------------------------------------------------------------------
// Prep kernel: pre-format conv weights into 32x32x16 MFMA B-fragment layout
// (f16 hi/lo-scaled limbs) + folded BN constants.
//   w1f: [20 kstep][2 limb][64 lane][8]  (K=320, N=32)   40960 B
//   w2f: [ 6 kstep][2 limb][64 lane][8]  (K=96,  N=16+16 zero pad) 12288 B
//   sb : s1[32] b1[32] s2[16] b2[16] f32
// B-frag mapping: lane l -> col n = l&31, k = (l>>5)*8 + j
// ---------------------------------------------------------------------------
__global__ __launch_bounds__(256) void geo_prep_kernel(
    const float* __restrict__ k1, const float* __restrict__ c1b,
    const float* __restrict__ bn1s, const float* __restrict__ bn1b,
    const float* __restrict__ bn1m, const float* __restrict__ bn1v,
    const float* __restrict__ k2, const float* __restrict__ c2b,
    const float* __restrict__ bn2s, const float* __restrict__ bn2b,
    const float* __restrict__ bn2m, const float* __restrict__ bn2v,
    unsigned short* __restrict__ w1f, unsigned short* __restrict__ w2f,
    float* __restrict__ sb)
{
    const int tid = threadIdx.x;
    for (int e = tid; e < 20 * 64; e += 256) {
        const int ks = e >> 6, l = e & 63;
        const int lh = l >> 5, n = l & 31;
        for (int j = 0; j < 8; ++j) {
            const int kg = ks * 16 + lh * 8 + j;       // kg = w*64+ci, 0..319
            unsigned short h, lo; split2h(k1[kg * 32 + n], h, lo);
            w1f[((ks * 2 + 0) * 64 + l) * 8 + j] = h;
            w1f[((ks * 2 + 1) * 64 + l) * 8 + j] = lo;
        }
    }
    for (int e = tid; e < 6 * 64; e += 256) {
        const int ks = e >> 6, l = e & 63;
        const int lh = l >> 5, n = l & 31;
        for (int j = 0; j < 8; ++j) {
            const int kg = ks * 16 + lh * 8 + j;       // kg = tap*32+ci2, 0..95
            const float v = (n < 16) ? k2[kg * 16 + n] : 0.0f;
            unsigned short h, lo; split2h(v, h, lo);
            w2f[((ks * 2 + 0) * 64 + l) * 8 + j] = h;
            w2f[((ks * 2 + 1) * 64 + l) * 8 + j] = lo;
        }
    }
    if (tid < 32) {
        const float s1 = bn1s[tid] * (1.0f / sqrtf(bn1v[tid] + 1e-5f));
        sb[tid]      = s1;
        sb[32 + tid] = bn1b[tid] + (c1b[tid] - bn1m[tid]) * s1;
    }
    if (tid < 16) {
        const float s2 = bn2s[tid] * (1.0f / sqrtf(bn2v[tid] + 1e-5f));
        sb[64 + tid] = s2;
        sb[80 + tid] = bn2b[tid] + (c2b[tid] - bn2m[tid]) * s2;
    }
}

// ---------------------------------------------------------------------------
// Conv kernel: 1 batch row/block, 256 threads = 4 waves.
//   waves 0,1: conv1 (frag = wave, 32 t-rows each, full K=320; epilogue of
//              previous chunk at phase top from live accumulators)
//   waves 2,3: x staging (chunk i+1) + conv2 at lag 3 (frag = wave-2)
// 1 barrier per iteration, 8 iterations of 64-t chunks.
// LDS: x f16-limb dbuf [2][68][64] x2 (34 KB) + c1 4-slot ring [4][65][40]
// x2 (40.6 KB, row 80 B for bank spread, slot0 row64 = zero row). 74.6 KB.
// ---------------------------------------------------------------------------
struct ConvSmem {
    unsigned short xh[2][68][64], xl[2][68][64];
    unsigned short c1h[4][65][40], c1l[4][65][40];
};

#define STAGE_F4 (68 * 16)   // float4 groups per chunk slab (68 rows x 16)

__device__ __forceinline__ void stage_chunk(ConvSmem& sm, const float* __restrict__ xrow,
                                            int chunk, int start, int stride) {
    const int buf = chunk & 1;
    const int t0 = chunk * 64;
    for (int fi = start; fi < STAGE_F4; fi += stride) {
        const int s = fi >> 4, cq = fi & 15;
        const int tabs = t0 - 2 + s;
        float4 v = {0.f, 0.f, 0.f, 0.f};
        if (tabs >= 0 && tabs < T_LEN)
            v = *reinterpret_cast<const float4*>(xrow + (size_t)tabs * 64 + cq * 4);
        unsigned short h0,l0,h1,l1,h2,l2,h3,l3;
        split2h(v.x, h0, l0); split2h(v.y, h1, l1);
        split2h(v.z, h2, l2); split2h(v.w, h3, l3);
        const int off = (((cq >> 1) ^ (s & 7)) * 8) + (cq & 1) * 4;
        ushort4 hv = {h0, h1, h2, h3}, lv = {l0, l1, l2, l3};
        *reinterpret_cast<ushort4*>(&sm.xh[buf][s][off]) = hv;
        *reinterpret_cast<ushort4*>(&sm.xl[buf][s][off]) = lv;
    }
}

#define MFMA32(A, B, C) __builtin_amdgcn_mfma_f32_32x32x16_f16((A), (B), (C), 0, 0, 0)

__device__ __forceinline__ void conv1_chunk(ConvSmem& sm, int buf, int frag, int lane,
                                            const f16x8* __restrict__ w1v,
                                            f32x16& am, f32x16& ca, f32x16& cb) {
    const int l31 = lane & 31, lh = lane >> 5;
#pragma unroll
    for (int q = 0; q < 16; ++q) { am[q] = 0.f; ca[q] = 0.f; cb[q] = 0.f; }
    f16x8 bh[2], bl[2], ah[2], al[2];
    // A-frag: row = l&31 (t), k = lh*8+j;  x slab row s = frag*32+l31+w, 16B-block swizzle
    {
        const int kb = lh * 8;
        const int s = frag * 32 + l31 + (kb >> 6);
        const int off = ((((kb & 63) >> 3) ^ (s & 7)) * 8);
        ah[0] = *reinterpret_cast<const f16x8*>(&sm.xh[buf][s][off]);
        al[0] = *reinterpret_cast<const f16x8*>(&sm.xl[buf][s][off]);
        bh[0] = w1v[0 * 64 + lane];
        bl[0] = w1v[1 * 64 + lane];
    }
#pragma unroll
    for (int ks = 0; ks < 20; ++ks) {
        const int cur = ks & 1, nxt = cur ^ 1;
        if (ks < 19) {
            const int kb = (ks + 1) * 16 + lh * 8;
            const int s = frag * 32 + l31 + (kb >> 6);
            const int off = ((((kb & 63) >> 3) ^ (s & 7)) * 8);
            ah[nxt] = *reinterpret_cast<const f16x8*>(&sm.xh[buf][s][off]);
            al[nxt] = *reinterpret_cast<const f16x8*>(&sm.xl[buf][s][off]);
            bh[nxt] = w1v[((ks + 1) * 2 + 0) * 64 + lane];
            bl[nxt] = w1v[((ks + 1) * 2 + 1) * 64 + lane];
        }
        am = MFMA32(ah[cur], bh[cur], am);
        ca = MFMA32(ah[cur], bl[cur], ca);
        cb = MFMA32(al[cur], bh[cur], cb);
    }
}

__device__ __forceinline__ void conv1_epi(ConvSmem& sm, int pc, int frag, int lane,
                                          float s1, float b1,
                                          const f32x16& am, const f32x16& ca, const f32x16& cb) {
    const int c = lane & 31, lh = lane >> 5;
    const int slot = pc & 3;
#pragma unroll
    for (int reg = 0; reg < 16; ++reg) {
        const int srow = frag * 32 + (reg & 3) + 8 * (reg >> 2) + 4 * lh;  // C: row map
        float v = am[reg] + (ca[reg] + cb[reg]) * (1.0f / 4096.0f);
        v = fmaxf(v * s1 + b1, 0.0f);
        unsigned short h, lo; split2h(v, h, lo);
        const int ui = (((c >> 3) ^ (srow & 3)) * 8) + (c & 7);
        sm.c1h[slot][srow][ui] = h;
        sm.c1l[slot][srow][ui] = lo;
    }
}

__device__ __forceinline__ void conv2_chunk(ConvSmem& sm, int cc, int frag, int lane,
                                            const f16x8* __restrict__ w2v,
                                            float* __restrict__ erow, float s2, float b2) {
    const int l31 = lane & 31, lh = lane >> 5;
    f32x16 am, ca, cb;
#pragma unroll
    for (int q = 0; q < 16; ++q) { am[q] = 0.f; ca[q] = 0.f; cb[q] = 0.f; }
#pragma unroll
    for (int ks = 0; ks < 6; ++ks) {
        const int kb = ks * 16 + lh * 8;
        const int tap = kb >> 5;
        const int gr = cc * 64 + frag * 32 + l31 + tap - 1;   // global conv1 row
        int slot, r;
        if (gr < 0 || gr >= T_LEN) { slot = 0; r = 64; }      // zero row
        else { slot = (gr >> 6) & 3; r = gr & 63; }
        const int off = ((((kb & 31) >> 3) ^ (r & 3)) * 8);
        f16x8 ah = *reinterpret_cast<const f16x8*>(&sm.c1h[slot][r][off]);
        f16x8 al = *reinterpret_cast<const f16x8*>(&sm.c1l[slot][r][off]);
        f16x8 bh = w2v[(ks * 2 + 0) * 64 + lane];
        f16x8 bl = w2v[(ks * 2 + 1) * 64 + lane];
        am = MFMA32(ah, bh, am);
        ca = MFMA32(ah, bl, ca);
        cb = MFMA32(al, bh, cb);
    }
    if (l31 < 16) {
#pragma unroll
        for (int reg = 0; reg < 16; ++reg) {
            const int t = cc * 64 + frag * 32 + (reg & 3) + 8 * (reg >> 2) + 4 * lh;
            float v = am[reg] + (ca[reg] + cb[reg]) * (1.0f / 4096.0f);
            v = fmaxf(v * s2 + b2, 0.0f);
            erow[(size_t)l31 * T_LEN + t] = v;
        }
    }
}

__global__ __launch_bounds__(256, 2) void geo_alif_conv_kernel(
    const float* __restrict__ x_eeg,
    const unsigned short* __restrict__ w1f, const unsigned short* __restrict__ w2f,
    const float* __restrict__ sb, float* __restrict__ e_ws)
{
    __shared__ ConvSmem sm;
    const int tid = threadIdx.x, lane = tid & 63, wv = tid >> 6;
    const int l31 = lane & 31;
    const float* xrow = x_eeg + (size_t)blockIdx.x * (T_LEN * 64);
    float* erow = e_ws + (size_t)blockIdx.x * (16 * T_LEN);

    // prologue: stage chunk 0 (all 256 threads) + init the c1 zero row
    stage_chunk(sm, xrow, 0, tid, 256);
    if (tid < 40) { sm.c1h[0][64][tid] = 0; sm.c1l[0][64][tid] = 0; }
    __syncthreads();

    if (wv < 2) {
        const int frag = wv;
        const float s1 = sb[l31], b1 = sb[32 + l31];
        const f16x8* w1v = reinterpret_cast<const f16x8*>(w1f);
        f32x16 am, ca, cb;
        for (int i = 0; i <= 7; ++i) {
            if (i >= 1 && i <= 5) conv1_epi(sm, i - 1, frag, lane, s1, b1, am, ca, cb);
            if (i <= 4)           conv1_chunk(sm, i & 1, frag, lane, w1v, am, ca, cb);
            __syncthreads();
        }
    } else {
        const int frag = wv - 2;
        const float s2 = (l31 < 16) ? sb[64 + l31] : 0.0f;
        const float b2 = (l31 < 16) ? sb[80 + l31] : 0.0f;
        const f16x8* w2v = reinterpret_cast<const f16x8*>(w2f);
        for (int i = 0; i <= 7; ++i) {
            if (i <= 3) stage_chunk(sm, xrow, i + 1, tid - 128, 128);
            if (i >= 3) conv2_chunk(sm, i - 3, frag, lane, w2v, erow, s2, b2);
            __syncthreads();
        }
    }
}

// ---------------------------------------------------------------------------
// Kernel 2: geo gate + ALIF scan + windowed diff-pool + fc1 + fc2 (unchanged)
// ---------------------------------------------------------------------------
__global__ __launch_bounds__(256) void geo_alif_scan_kernel(
    const float* __restrict__ e_ws, const float* __restrict__ x_geo,
    const float* __restrict__ geoW, const float* __restrict__ geob,
    const float* __restrict__ gam,
    const float* __restrict__ fc1W, const float* __restrict__ fc1b,
    const float* __restrict__ fc2W, const float* __restrict__ fc2b,
    float* __restrict__ out)
{
    __shared__ float gW[18][16];
    __shared__ float geo_s[16][16][16];
    __shared__ float dp[16][160];
    __shared__ float h1s[16][64];

    const int tid = threadIdx.x;
    for (int i = tid; i < 288; i += 256) gW[i / 16][i & 15] = geoW[i];
    __syncthreads();

    const int r = tid >> 4, h = tid & 15;
    const int b = blockIdx.x * 16 + r;
    const float* ep = e_ws + ((size_t)b * 16 + h) * T_LEN;
    const float gmv = gam[h];

    float mem = 0.f, eta = 0.f, li = 0.f, prev = 0.f, acc = 0.f;

    for (int c = 0; c < 20; ++c) {
        {
            const int rg = tid >> 4, tl = tid & 15;
            const int t = c * 16 + tl;
            const float* xg = x_geo + ((size_t)(blockIdx.x * 16 + rg) * T_LEN + t) * 18;
            float xv[18];
#pragma unroll
            for (int i = 0; i < 18; ++i) xv[i] = xg[i];
#pragma unroll
            for (int hh = 0; hh < 16; ++hh) {
                float a = geob[hh];
#pragma unroll
                for (int i = 0; i < 18; ++i) a = fmaf(xv[i], gW[i][hh], a);
                geo_s[rg][tl][hh] = 1.f / (1.f + expf(-a));
            }
        }
        __syncthreads();

        const float* ec = ep + c * 16;
#pragma unroll
        for (int q = 0; q < 4; ++q) {
            float4 ev = *reinterpret_cast<const float4*>(ec + q * 4);
            float evs[4] = {ev.x, ev.y, ev.z, ev.w};
#pragma unroll
            for (int u = 0; u < 4; ++u) {
                const int tt = c * 16 + q * 4 + u;
                const float g = geo_s[r][q * 4 + u][h];
                eta = 0.36f * eta + 0.64f * prev;
                const float th = 0.5f + 1.8f * eta - gmv * g;
                mem = 0.8f * mem + evs[u];
                const bool sp = (mem >= th);
                const float spk = sp ? 1.f : 0.f;
                prev = spk;
                mem = sp ? 0.f : mem;
                li = 0.9f * li + spk;
                acc += ((tt & 31) < 16) ? -li : li;
                if ((tt & 31) == 31) {
                    dp[r][h * 10 + (tt >> 5)] = acc * 0.0625f;
                    acc = 0.f;
                }
            }
        }
        __syncthreads();
    }

    {
        const int rr = tid >> 4, j0 = tid & 15;
        float a0 = fc1b[j0], a1 = fc1b[j0 + 16], a2 = fc1b[j0 + 32], a3 = fc1b[j0 + 48];
        for (int f = 0; f < 160; ++f) {
            const float d = dp[rr][f];
            a0 = fmaf(d, fc1W[f * 64 + j0],      a0);
            a1 = fmaf(d, fc1W[f * 64 + j0 + 16], a1);
            a2 = fmaf(d, fc1W[f * 64 + j0 + 32], a2);
            a3 = fmaf(d, fc1W[f * 64 + j0 + 48], a3);
        }
        h1s[rr][j0]      = fmaxf(a0, 0.f);
        h1s[rr][j0 + 16] = fmaxf(a1, 0.f);
        h1s[rr][j0 + 32] = fmaxf(a2, 0.f);
        h1s[rr][j0 + 48] = fmaxf(a3, 0.f);
    }
    __syncthreads();

    if (tid < 64) {
        const int rr = tid >> 2, o = tid & 3;
        float a = fc2b[o];
#pragma unroll
        for (int j = 0; j < 64; ++j) a = fmaf(h1s[rr][j], fc2W[j * 4 + o], a);
        out[((size_t)(blockIdx.x * 16 + rr)) * 4 + o] = a;
    }
}

extern "C" void kernel_launch(void* const* d_in, const int* in_sizes, int n_in,
                              void* d_out, int out_size, void* d_ws, size_t ws_size,
                              hipStream_t stream) {
    (void)in_sizes; (void)n_in; (void)out_size; (void)ws_size;
    const float* x_eeg = (const float*)d_in[0];
    const float* x_geo = (const float*)d_in[1];
    const float* k1    = (const float*)d_in[2];
    const float* c1b   = (const float*)d_in[3];
    const float* bn1s  = (const float*)d_in[4];
    const float* bn1b  = (const float*)d_in[5];
    const float* bn1m  = (const float*)d_in[6];
    const float* bn1v  = (const float*)d_in[7];
    const float* k2    = (const float*)d_in[8];
    const float* c2b   = (const float*)d_in[9];
    const float* bn2s  = (const float*)d_in[10];
    const float* bn2b  = (const float*)d_in[11];
    const float* bn2m  = (const float*)d_in[12];
    const float* bn2v  = (const float*)d_in[13];
    const float* geoW  = (const float*)d_in[14];
    const float* geob  = (const float*)d_in[15];
    const float* gam   = (const float*)d_in[16];
    const float* fc1W  = (const float*)d_in[17];
    const float* fc1b  = (const float*)d_in[18];
    const float* fc2W  = (const float*)d_in[19];
    const float* fc2b  = (const float*)d_in[20];

    // workspace layout
    char* wsb = (char*)d_ws;
    unsigned short* w1f = (unsigned short*)(wsb);          // 40960 B
    unsigned short* w2f = (unsigned short*)(wsb + 40960);  // 12288 B
    float* sb           = (float*)(wsb + 53248);           // 384 B
    float* e_ws         = (float*)(wsb + 65536);           // 4096*16*320*4 = 83.9 MB

    geo_prep_kernel<<<1, 256, 0, stream>>>(
        k1, c1b, bn1s, bn1b, bn1m, bn1v,
        k2, c2b, bn2s, bn2b, bn2m, bn2v, w1f, w2f, sb);

    geo_alif_conv_kernel<<<4096, 256, 0, stream>>>(x_eeg, w1f, w2f, sb, e_ws);

    geo_alif_scan_kernel<<<256, 256, 0, stream>>>(
        e_ws, x_geo, geoW, geob, gam, fc1W, fc1b, fc2W, fc2b, (float*)d_out);
}

// Round 8
// 286.184 us; speedup vs baseline: 2.0001x; 1.3693x over previous
//
#include <hip/hip_runtime.h>

typedef _Float16 f16;
typedef __attribute__((ext_vector_type(8))) _Float16 f16x8;
typedef __attribute__((ext_vector_type(16))) float f32x16;

#define T_LEN 320

// ---------------------------------------------------------------------------
// f16 two-limb split with scaled low limb: v = h + (l/4096), residual ~2^-24|v|
// ---------------------------------------------------------------------------
__device__ __forceinline__ void split2h(float v, unsigned short &h, unsigned short &l) {
    f16 hh = (f16)v;
    f16 ll = (f16)((v - (float)hh) * 4096.0f);
    h = __builtin_bit_cast(unsigned short, hh);
    l = __builtin_bit_cast(unsigned short, ll);
}

// ---------------------------------------------------------------------------
// Prep kernel: pre-format conv weights into 32x32x16 MFMA B-fragment layout
// (f16 hi/lo-scaled limbs) + folded BN constants.
//   w1f: [20 kstep][2 limb][64 lane][8]  (K=320, N=32)   40960 B
//   w2f: [ 6 kstep][2 limb][64 lane][8]  (K=96,  N=16+16 zero pad) 12288 B
//   sb : s1[32] b1[32] s2[16] b2[16] f32
// B-frag mapping: lane l -> col n = l&31, k = (l>>5)*8 + j
// ---------------------------------------------------------------------------
__global__ __launch_bounds__(256) void geo_prep_kernel(
    const float* __restrict__ k1, const float* __restrict__ c1b,
    const float* __restrict__ bn1s, const float* __restrict__ bn1b,
    const float* __restrict__ bn1m, const float* __restrict__ bn1v,
    const float* __restrict__ k2, const float* __restrict__ c2b,
    const float* __restrict__ bn2s, const float* __restrict__ bn2b,
    const float* __restrict__ bn2m, const float* __restrict__ bn2v,
    unsigned short* __restrict__ w1f, unsigned short* __restrict__ w2f,
    float* __restrict__ sb)
{
    const int tid = threadIdx.x;
    for (int e = tid; e < 20 * 64; e += 256) {
        const int ks = e >> 6, l = e & 63;
        const int lh = l >> 5, n = l & 31;
        for (int j = 0; j < 8; ++j) {
            const int kg = ks * 16 + lh * 8 + j;       // kg = w*64+ci, 0..319
            unsigned short h, lo; split2h(k1[kg * 32 + n], h, lo);
            w1f[((ks * 2 + 0) * 64 + l) * 8 + j] = h;
            w1f[((ks * 2 + 1) * 64 + l) * 8 + j] = lo;
        }
    }
    for (int e = tid; e < 6 * 64; e += 256) {
        const int ks = e >> 6, l = e & 63;
        const int lh = l >> 5, n = l & 31;
        for (int j = 0; j < 8; ++j) {
            const int kg = ks * 16 + lh * 8 + j;       // kg = tap*32+ci2, 0..95
            const float v = (n < 16) ? k2[kg * 16 + n] : 0.0f;
            unsigned short h, lo; split2h(v, h, lo);
            w2f[((ks * 2 + 0) * 64 + l) * 8 + j] = h;
            w2f[((ks * 2 + 1) * 64 + l) * 8 + j] = lo;
        }
    }
    if (tid < 32) {
        const float s1 = bn1s[tid] * (1.0f / sqrtf(bn1v[tid] + 1e-5f));
        sb[tid]      = s1;
        sb[32 + tid] = bn1b[tid] + (c1b[tid] - bn1m[tid]) * s1;
    }
    if (tid < 16) {
        const float s2 = bn2s[tid] * (1.0f / sqrtf(bn2v[tid] + 1e-5f));
        sb[64 + tid] = s2;
        sb[80 + tid] = bn2b[tid] + (c2b[tid] - bn2m[tid]) * s2;
    }
}

// ---------------------------------------------------------------------------
// Conv kernel: 1 batch row/block, 256 threads = 4 waves.
//   waves 0,1: conv1 (frag = wave, 32 t-rows each, full K=320; B-frag reg
//              pipeline depth 5 (global/L2), A-frag ds pipeline depth 3;
//              epilogue of prev chunk runs under the prologue loads)
//   waves 2,3: batched x staging (chunk i+1) + conv2 at lag 3 (w2 in regs)
// 1 barrier per iteration, 8 iterations of 64-t chunks.
// ---------------------------------------------------------------------------
struct ConvSmem {
    unsigned short xh[2][68][64], xl[2][68][64];
    unsigned short c1h[4][65][40], c1l[4][65][40];
};

#define STAGE_F4 (68 * 16)   // float4 groups per chunk slab (68 rows x 16)

// batched staging: issue all loads first, then split+store
template<int NTH>
__device__ __forceinline__ void stage_chunk(ConvSmem& sm, const float* __restrict__ xrow,
                                            int chunk, int t) {
    const int buf = chunk & 1;
    const int t0 = chunk * 64;
    constexpr int NQ = (STAGE_F4 + NTH - 1) / NTH;
    float4 v[NQ];
#pragma unroll
    for (int q = 0; q < NQ; ++q) {
        const int fi = t + q * NTH;
        float4 tv = {0.f, 0.f, 0.f, 0.f};
        if (fi < STAGE_F4) {
            const int s = fi >> 4;
            const int tabs = t0 - 2 + s;
            if (tabs >= 0 && tabs < T_LEN)
                tv = *reinterpret_cast<const float4*>(xrow + (size_t)tabs * 64 + (fi & 15) * 4);
        }
        v[q] = tv;
    }
#pragma unroll
    for (int q = 0; q < NQ; ++q) {
        const int fi = t + q * NTH;
        if (fi < STAGE_F4) {
            const int s = fi >> 4, cq = fi & 15;
            unsigned short h0,l0,h1,l1,h2,l2,h3,l3;
            split2h(v[q].x, h0, l0); split2h(v[q].y, h1, l1);
            split2h(v[q].z, h2, l2); split2h(v[q].w, h3, l3);
            const int off = (((cq >> 1) ^ (s & 7)) * 8) + (cq & 1) * 4;
            ushort4 hv = {h0, h1, h2, h3}, lv = {l0, l1, l2, l3};
            *reinterpret_cast<ushort4*>(&sm.xh[buf][s][off]) = hv;
            *reinterpret_cast<ushort4*>(&sm.xl[buf][s][off]) = lv;
        }
    }
}

#define MFMA32(A, B, C) __builtin_amdgcn_mfma_f32_32x32x16_f16((A), (B), (C), 0, 0, 0)

__device__ __forceinline__ void conv1_epi(ConvSmem& sm, int pc, int frag, int lane,
                                          float s1, float b1,
                                          const f32x16& am, const f32x16& ca, const f32x16& cb) {
    const int c = lane & 31, lh = lane >> 5;
    const int slot = pc & 3;
#pragma unroll
    for (int reg = 0; reg < 16; ++reg) {
        const int srow = frag * 32 + (reg & 3) + 8 * (reg >> 2) + 4 * lh;  // C: row map
        float v = am[reg] + (ca[reg] + cb[reg]) * (1.0f / 4096.0f);
        v = fmaxf(v * s1 + b1, 0.0f);
        unsigned short h, lo; split2h(v, h, lo);
        const int ui = (((c >> 3) ^ (srow & 3)) * 8) + (c & 7);
        sm.c1h[slot][srow][ui] = h;
        sm.c1l[slot][srow][ui] = lo;
    }
}

__device__ __forceinline__ void conv2_chunk(ConvSmem& sm, int cc, int frag, int lane,
                                            const f16x8 (&w2h)[6], const f16x8 (&w2l)[6],
                                            float* __restrict__ erow, float s2, float b2) {
    const int l31 = lane & 31, lh = lane >> 5;
    f32x16 am, ca, cb;
#pragma unroll
    for (int q = 0; q < 16; ++q) { am[q] = 0.f; ca[q] = 0.f; cb[q] = 0.f; }
#pragma unroll
    for (int ks = 0; ks < 6; ++ks) {
        const int kb = ks * 16 + lh * 8;
        const int tap = kb >> 5;
        const int gr = cc * 64 + frag * 32 + l31 + tap - 1;   // global conv1 row
        int slot, r;
        if (gr < 0 || gr >= T_LEN) { slot = 0; r = 64; }      // zero row
        else { slot = (gr >> 6) & 3; r = gr & 63; }
        const int off = ((((kb & 31) >> 3) ^ (r & 3)) * 8);
        f16x8 ah = *reinterpret_cast<const f16x8*>(&sm.c1h[slot][r][off]);
        f16x8 al = *reinterpret_cast<const f16x8*>(&sm.c1l[slot][r][off]);
        am = MFMA32(ah, w2h[ks], am);
        ca = MFMA32(ah, w2l[ks], ca);
        cb = MFMA32(al, w2h[ks], cb);
    }
    if (l31 < 16) {
#pragma unroll
        for (int reg = 0; reg < 16; ++reg) {
            const int t = cc * 64 + frag * 32 + (reg & 3) + 8 * (reg >> 2) + 4 * lh;
            float v = am[reg] + (ca[reg] + cb[reg]) * (1.0f / 4096.0f);
            v = fmaxf(v * s2 + b2, 0.0f);
            erow[(size_t)l31 * T_LEN + t] = v;
        }
    }
}

__global__ __launch_bounds__(256, 2) void geo_alif_conv_kernel(
    const float* __restrict__ x_eeg,
    const unsigned short* __restrict__ w1f, const unsigned short* __restrict__ w2f,
    const float* __restrict__ sb, float* __restrict__ e_ws)
{
    __shared__ ConvSmem sm;
    const int tid = threadIdx.x, lane = tid & 63, wv = tid >> 6;
    const int l31 = lane & 31, lh = lane >> 5;
    const float* xrow = x_eeg + (size_t)blockIdx.x * (T_LEN * 64);
    float* erow = e_ws + (size_t)blockIdx.x * (16 * T_LEN);

    // prologue: stage chunk 0 (all 256 threads) + init the c1 zero row
    stage_chunk<256>(sm, xrow, 0, tid);
    if (tid < 40) { sm.c1h[0][64][tid] = 0; sm.c1l[0][64][tid] = 0; }
    __syncthreads();

    if (wv < 2) {
        // ---------------- conv1 role ----------------
        const int frag = wv;
        const float s1 = sb[l31], b1 = sb[32 + l31];
        const f16x8* w1v = reinterpret_cast<const f16x8*>(w1f);
        f32x16 am, ca, cb;
        for (int i = 0; i <= 7; ++i) {
            const bool doc = (i <= 4);
            f16x8 pbh[5], pbl[5], pah[3], pal[3];
            if (doc) {
                const int buf = i & 1;
                // issue prologue loads (hidden under the epilogue's VALU)
#pragma unroll
                for (int p = 0; p < 5; ++p) {
                    pbh[p] = w1v[(p * 2 + 0) * 64 + lane];
                    pbl[p] = w1v[(p * 2 + 1) * 64 + lane];
                }
#pragma unroll
                for (int p = 0; p < 3; ++p) {
                    const int kb = p * 16 + lh * 8;
                    const int s = frag * 32 + l31 + (kb >> 6);
                    const int off = ((((kb & 63) >> 3) ^ (s & 7)) * 8);
                    pah[p] = *reinterpret_cast<const f16x8*>(&sm.xh[buf][s][off]);
                    pal[p] = *reinterpret_cast<const f16x8*>(&sm.xl[buf][s][off]);
                }
            }
            if (i >= 1 && i <= 5) conv1_epi(sm, i - 1, frag, lane, s1, b1, am, ca, cb);
            if (doc) {
                const int buf = i & 1;
#pragma unroll
                for (int q = 0; q < 16; ++q) { am[q] = 0.f; ca[q] = 0.f; cb[q] = 0.f; }
#pragma unroll
                for (int ks = 0; ks < 20; ++ks) {
                    const f16x8 xh_ = pah[ks % 3], xl_ = pal[ks % 3];
                    const f16x8 wh_ = pbh[ks % 5], wl_ = pbl[ks % 5];
                    am = MFMA32(xh_, wh_, am);
                    ca = MFMA32(xh_, wl_, ca);
                    cb = MFMA32(xl_, wh_, cb);
                    if (ks < 17) {          // refill A for ks+3 (slot ks%3)
                        const int kb = (ks + 3) * 16 + lh * 8;
                        const int s = frag * 32 + l31 + (kb >> 6);
                        const int off = ((((kb & 63) >> 3) ^ (s & 7)) * 8);
                        pah[ks % 3] = *reinterpret_cast<const f16x8*>(&sm.xh[buf][s][off]);
                        pal[ks % 3] = *reinterpret_cast<const f16x8*>(&sm.xl[buf][s][off]);
                    }
                    if (ks < 15) {          // refill B for ks+5 (slot ks%5)
                        pbh[ks % 5] = w1v[((ks + 5) * 2 + 0) * 64 + lane];
                        pbl[ks % 5] = w1v[((ks + 5) * 2 + 1) * 64 + lane];
                    }
                }
            }
            __syncthreads();
        }
    } else {
        // ---------------- staging + conv2 role ----------------
        const int frag = wv - 2;
        const float s2 = (l31 < 16) ? sb[64 + l31] : 0.0f;
        const float b2 = (l31 < 16) ? sb[80 + l31] : 0.0f;
        const f16x8* w2v = reinterpret_cast<const f16x8*>(w2f);
        f16x8 w2h[6], w2l[6];
#pragma unroll
        for (int p = 0; p < 6; ++p) {       // load once per block
            w2h[p] = w2v[(p * 2 + 0) * 64 + lane];
            w2l[p] = w2v[(p * 2 + 1) * 64 + lane];
        }
        for (int i = 0; i <= 7; ++i) {
            if (i <= 3) stage_chunk<128>(sm, xrow, i + 1, tid - 128);
            if (i >= 3) conv2_chunk(sm, i - 3, frag, lane, w2h, w2l, erow, s2, b2);
            __syncthreads();
        }
    }
}

// ---------------------------------------------------------------------------
// Kernel 2: geo gate + ALIF scan + windowed diff-pool + fc1 + fc2 (unchanged)
// ---------------------------------------------------------------------------
__global__ __launch_bounds__(256) void geo_alif_scan_kernel(
    const float* __restrict__ e_ws, const float* __restrict__ x_geo,
    const float* __restrict__ geoW, const float* __restrict__ geob,
    const float* __restrict__ gam,
    const float* __restrict__ fc1W, const float* __restrict__ fc1b,
    const float* __restrict__ fc2W, const float* __restrict__ fc2b,
    float* __restrict__ out)
{
    __shared__ float gW[18][16];
    __shared__ float geo_s[16][16][16];
    __shared__ float dp[16][160];
    __shared__ float h1s[16][64];

    const int tid = threadIdx.x;
    for (int i = tid; i < 288; i += 256) gW[i / 16][i & 15] = geoW[i];
    __syncthreads();

    const int r = tid >> 4, h = tid & 15;
    const int b = blockIdx.x * 16 + r;
    const float* ep = e_ws + ((size_t)b * 16 + h) * T_LEN;
    const float gmv = gam[h];

    float mem = 0.f, eta = 0.f, li = 0.f, prev = 0.f, acc = 0.f;

    for (int c = 0; c < 20; ++c) {
        {
            const int rg = tid >> 4, tl = tid & 15;
            const int t = c * 16 + tl;
            const float* xg = x_geo + ((size_t)(blockIdx.x * 16 + rg) * T_LEN + t) * 18;
            float xv[18];
#pragma unroll
            for (int i = 0; i < 18; ++i) xv[i] = xg[i];
#pragma unroll
            for (int hh = 0; hh < 16; ++hh) {
                float a = geob[hh];
#pragma unroll
                for (int i = 0; i < 18; ++i) a = fmaf(xv[i], gW[i][hh], a);
                geo_s[rg][tl][hh] = 1.f / (1.f + expf(-a));
            }
        }
        __syncthreads();

        const float* ec = ep + c * 16;
#pragma unroll
        for (int q = 0; q < 4; ++q) {
            float4 ev = *reinterpret_cast<const float4*>(ec + q * 4);
            float evs[4] = {ev.x, ev.y, ev.z, ev.w};
#pragma unroll
            for (int u = 0; u < 4; ++u) {
                const int tt = c * 16 + q * 4 + u;
                const float g = geo_s[r][q * 4 + u][h];
                eta = 0.36f * eta + 0.64f * prev;
                const float th = 0.5f + 1.8f * eta - gmv * g;
                mem = 0.8f * mem + evs[u];
                const bool sp = (mem >= th);
                const float spk = sp ? 1.f : 0.f;
                prev = spk;
                mem = sp ? 0.f : mem;
                li = 0.9f * li + spk;
                acc += ((tt & 31) < 16) ? -li : li;
                if ((tt & 31) == 31) {
                    dp[r][h * 10 + (tt >> 5)] = acc * 0.0625f;
                    acc = 0.f;
                }
            }
        }
        __syncthreads();
    }

    {
        const int rr = tid >> 4, j0 = tid & 15;
        float a0 = fc1b[j0], a1 = fc1b[j0 + 16], a2 = fc1b[j0 + 32], a3 = fc1b[j0 + 48];
        for (int f = 0; f < 160; ++f) {
            const float d = dp[rr][f];
            a0 = fmaf(d, fc1W[f * 64 + j0],      a0);
            a1 = fmaf(d, fc1W[f * 64 + j0 + 16], a1);
            a2 = fmaf(d, fc1W[f * 64 + j0 + 32], a2);
            a3 = fmaf(d, fc1W[f * 64 + j0 + 48], a3);
        }
        h1s[rr][j0]      = fmaxf(a0, 0.f);
        h1s[rr][j0 + 16] = fmaxf(a1, 0.f);
        h1s[rr][j0 + 32] = fmaxf(a2, 0.f);
        h1s[rr][j0 + 48] = fmaxf(a3, 0.f);
    }
    __syncthreads();

    if (tid < 64) {
        const int rr = tid >> 2, o = tid & 3;
        float a = fc2b[o];
#pragma unroll
        for (int j = 0; j < 64; ++j) a = fmaf(h1s[rr][j], fc2W[j * 4 + o], a);
        out[((size_t)(blockIdx.x * 16 + rr)) * 4 + o] = a;
    }
}

extern "C" void kernel_launch(void* const* d_in, const int* in_sizes, int n_in,
                              void* d_out, int out_size, void* d_ws, size_t ws_size,
                              hipStream_t stream) {
    (void)in_sizes; (void)n_in; (void)out_size; (void)ws_size;
    const float* x_eeg = (const float*)d_in[0];
    const float* x_geo = (const float*)d_in[1];
    const float* k1    = (const float*)d_in[2];
    const float* c1b   = (const float*)d_in[3];
    const float* bn1s  = (const float*)d_in[4];
    const float* bn1b  = (const float*)d_in[5];
    const float* bn1m  = (const float*)d_in[6];
    const float* bn1v  = (const float*)d_in[7];
    const float* k2    = (const float*)d_in[8];
    const float* c2b   = (const float*)d_in[9];
    const float* bn2s  = (const float*)d_in[10];
    const float* bn2b  = (const float*)d_in[11];
    const float* bn2m  = (const float*)d_in[12];
    const float* bn2v  = (const float*)d_in[13];
    const float* geoW  = (const float*)d_in[14];
    const float* geob  = (const float*)d_in[15];
    const float* gam   = (const float*)d_in[16];
    const float* fc1W  = (const float*)d_in[17];
    const float* fc1b  = (const float*)d_in[18];
    const float* fc2W  = (const float*)d_in[19];
    const float* fc2b  = (const float*)d_in[20];

    // workspace layout
    char* wsb = (char*)d_ws;
    unsigned short* w1f = (unsigned short*)(wsb);          // 40960 B
    unsigned short* w2f = (unsigned short*)(wsb + 40960);  // 12288 B
    float* sb           = (float*)(wsb + 53248);           // 384 B
    float* e_ws         = (float*)(wsb + 65536);           // 4096*16*320*4 = 83.9 MB

    geo_prep_kernel<<<1, 256, 0, stream>>>(
        k1, c1b, bn1s, bn1b, bn1m, bn1v,
        k2, c2b, bn2s, bn2b, bn2m, bn2v, w1f, w2f, sb);

    geo_alif_conv_kernel<<<4096, 256, 0, stream>>>(x_eeg, w1f, w2f, sb, e_ws);

    geo_alif_scan_kernel<<<256, 256, 0, stream>>>(
        e_ws, x_geo, geoW, geob, gam, fc1W, fc1b, fc2W, fc2b, (float*)d_out);
}